// Round 17
// baseline (60.276 us; speedup 1.0000x reference)
//
#include <hip/hip_runtime.h>

// SSIM, fused separable, v15 = R16 + CHAIN-SPLIT + LOAD-HOIST.
// R16 (packed fp32) hit 56.8us, VGPR 76, conflicts 0. Remaining stall is
// intra-row dependency serialization (wave issues ~32% of cycles at ~1.85
// resident waves/SIMD). This round: (1) QS accumulator chain split 14->7+7
// (all chains now depth 7), (2) both rows' 16 LDS window loads hoisted above
// both H-computes so ds_read latency overlaps row-0 compute. Pipeline
// otherwise identical: DMA pair staging, triple pair-buffer, counted
// vmcnt(4), masked packed Wp2 windows, EMIT-first, packed V-pass rings.

#define IMG_H 512
#define IMG_W 512
#define N_PLANES 48
#define KW 11
#define BLOCK 256
#define WAVE_COLS 64
#define STRIP_H 64
#define BLOCKS_X (IMG_W / (WAVE_COLS * 4))            // 2
#define BLOCKS_Y (IMG_H / STRIP_H)                    // 8
#define NBLK (N_PLANES * BLOCKS_X * BLOCKS_Y)         // 768
#define PAIRF 320          // floats per pair-buf: row0[img1 80|img2 80] row1[..]
#define C1_CONST 1.0e-4f
#define C2_CONST 9.0e-4f

typedef float v2f __attribute__((ext_vector_type(2)));
typedef float v4f __attribute__((ext_vector_type(4)));

typedef const __attribute__((address_space(1))) void GV;
typedef __attribute__((address_space(3))) void LV;

__device__ __forceinline__ void dma16(const float* g, float* l) {
  __builtin_amdgcn_global_load_lds((GV*)g, (LV*)l, 16, 0, 0);
}

__device__ __forceinline__ float bcastf(float x) {
  return __uint_as_float(__builtin_amdgcn_readfirstlane(__float_as_uint(x)));
}

#define VLO(V) __builtin_shufflevector(V, V, 0, 1)
#define VHI(V) __builtin_shufflevector(V, V, 2, 3)

// One packed 2-tap group with split QS chains (each accumulator depth 1/group).
#define PTAP(WJ, X1, X2) { \
    const v2f t1_ = (WJ) * (X1); const v2f t2_ = (WJ) * (X2); \
    M1 += t1_; M2 += t2_; \
    QS1 += t1_ * (X1); QS2 += t2_ * (X2); Q12 += t1_ * (X2); }

// Load one row's windows (img1 +0, img2 +80 from BP) into regs tagged N.
#define HLOAD(BP, N) \
    const v4f A0##N = *(const v4f*)((BP) + a); \
    const v4f B0##N = *(const v4f*)((BP) + 80 + a); \
    const v4f A1##N = *(const v4f*)((BP) + a + 4); \
    const v4f B1##N = *(const v4f*)((BP) + 80 + a + 4); \
    const v4f A2##N = *(const v4f*)((BP) + a + 8); \
    const v4f B2##N = *(const v4f*)((BP) + 80 + a + 8); \
    const v2f A3##N = *(const v2f*)((BP) + a + 12); \
    const v2f B3##N = *(const v2f*)((BP) + 80 + a + 12);

// H-pass compute from regs tagged N into ring slot SLOT (guarded by ROW).
#define HCOMP(ROW, SLOT, N) { \
  if ((ROW) >= 0 && (ROW) < IMG_H) { \
    v2f M1 = {0.f,0.f}, M2 = {0.f,0.f}; \
    v2f QS1 = {0.f,0.f}, QS2 = {0.f,0.f}, Q12 = {0.f,0.f}; \
    PTAP(Wp2[0], VLO(A0##N), VLO(B0##N)) PTAP(Wp2[1], VHI(A0##N), VHI(B0##N)) \
    PTAP(Wp2[2], VLO(A1##N), VLO(B1##N)) PTAP(Wp2[3], VHI(A1##N), VHI(B1##N)) \
    PTAP(Wp2[4], VLO(A2##N), VLO(B2##N)) PTAP(Wp2[5], VHI(A2##N), VHI(B2##N)) \
    PTAP(Wp2[6], A3##N, B3##N) \
    Pm[(SLOT)] = (v2f){M1.x + M1.y, M2.x + M2.y}; \
    Pq[(SLOT)] = (v2f){(QS1.x + QS1.y) + (QS2.x + QS2.y), Q12.x + Q12.y}; \
  } else { \
    Pm[(SLOT)] = (v2f){0.f, 0.f}; Pq[(SLOT)] = (v2f){0.f, 0.f}; } }

#define EMT(K, QQ) { const float w_ = wkr[(K)]; \
    vmP += w_ * Pm[(QQ)]; vqP += w_ * Pq[(QQ)]; }

// V-pass + SSIM for one output row whose tap-k ring slot is (OFF+K)%12.
#define EMITQ(OFF) { \
  v2f vmP = {0.f,0.f}, vqP = {0.f,0.f}; \
  EMT(0, ((OFF)+0)%12)  EMT(1, ((OFF)+1)%12)  EMT(2, ((OFF)+2)%12) \
  EMT(3, ((OFF)+3)%12)  EMT(4, ((OFF)+4)%12)  EMT(5, ((OFF)+5)%12) \
  EMT(6, ((OFF)+6)%12)  EMT(7, ((OFF)+7)%12)  EMT(8, ((OFF)+8)%12) \
  EMT(9, ((OFF)+9)%12)  EMT(10, ((OFF)+10)%12) \
  const float vm1_ = vmP.x, vm2_ = vmP.y, vqs_ = vqP.x, vq12_ = vqP.y; \
  const float mu11_ = vm1_ * vm1_; \
  const float mu22_ = vm2_ * vm2_; \
  const float mu12_ = vm1_ * vm2_; \
  const float musum_ = mu11_ + mu22_; \
  const float sigs_  = vqs_  - musum_; \
  const float sig12_ = vq12_ - mu12_; \
  const float num_ = (2.f * mu12_ + C1_CONST) * (2.f * sig12_ + C2_CONST); \
  const float den_ = (musum_ + C1_CONST) * (sigs_ + C2_CONST); \
  acc += num_ * __builtin_amdgcn_rcpf(den_); }

// One 2-row step, phase P = step % 6 (compile-time). EMIT-first (R15):
// 1) issue DMA pair (gr+4, gr+5) -> buf (P+2)%3
// 2) if EMIT: output rows gr-7, gr-6 (ring-only; fills the DMA wait)
// 3) vmcnt(4): pair (gr, gr+1) (issued 2 steps ago) complete in buf P%3
// 4) both rows' LDS window loads, then both H-computes (latency overlap)
#define STEP2(P, EMIT) { \
  { const int na_ = gr+4 < 0 ? 0 : (gr+4 > IMG_H-1 ? IMG_H-1 : gr+4); \
    const int nb_ = gr+5 < 0 ? 0 : (gr+5 > IMG_H-1 ? IMG_H-1 : gr+5); \
    if (lane < 40) { \
      float* d_ = slw + (((P)+2)%3) * PAIRF; \
      dma16(srcbase + (size_t)na_ * IMG_W, d_); \
      dma16(srcbase + (size_t)nb_ * IMG_W, d_ + 160); } } \
  if (EMIT) { EMITQ((2*(P))%12) EMITQ((2*(P)+1)%12) } \
  asm volatile("s_waitcnt vmcnt(4)" ::: "memory"); \
  __builtin_amdgcn_sched_barrier(0); \
  { const float* bp_ = slw + ((P)%3) * PAIRF; \
    HLOAD(bp_, 0) \
    HLOAD(bp_ + 160, 1) \
    HCOMP(gr,     (2*(P))%12,   0) \
    HCOMP(gr + 1, (2*(P)+1)%12, 1) } \
  gr += 2; }

__global__ __launch_bounds__(BLOCK) void ssim_strip_kernel(
    const float* __restrict__ img1,
    const float* __restrict__ img2,
    const float* __restrict__ kern2d,
    float* __restrict__ partial)
{
  // Wave-private triple pair-buffers: [wave][buf3][pair 320]. 15,360 B.
  __shared__ __align__(16) float slice[4][3][PAIRF];
  __shared__ float wk_lds[KW];
  __shared__ float wave_sums[BLOCK / 64];

  const int tid  = threadIdx.x;
  const int wid  = tid >> 6;
  const int lane = tid & 63;

  // 1D kernel = row sums of the normalized 2D kernel (== normalized 1D Gaussian).
  if (tid < KW) {
    float s = 0.f;
    #pragma unroll
    for (int j = 0; j < KW; ++j) s += kern2d[tid * KW + j];
    wk_lds[tid] = s;
  }
  __syncthreads();

  // V-pass weights, wave-uniform (SGPRs).
  float wkr[KW];
  #pragma unroll
  for (int k = 0; k < KW; ++k) wkr[k] = bcastf(wk_lds[k]);

  const int bid   = blockIdx.x;
  const int plane = bid / (BLOCKS_X * BLOCKS_Y);
  const int srem  = bid % (BLOCKS_X * BLOCKS_Y);
  const int y0    = (srem / BLOCKS_X) * STRIP_H;
  const int x0b   = (srem % BLOCKS_X) * (WAVE_COLS * 4);
  const float* __restrict__ p1 = img1 + (size_t)plane * IMG_H * IMG_W;
  const float* __restrict__ p2 = img2 + (size_t)plane * IMG_H * IMG_W;

  const int x0w   = x0b + wid * WAVE_COLS;   // wave's first column
  const int gx    = x0w + lane;              // this thread's output column
  const int wbase = x0w - 8;                 // slice float 0 <-> global col wbase

  // Lane's window: slice floats [a, a+13]; taps at e in [r, r+10].
  const int a = (lane + 3) & ~3;
  const int r = (lane + 3) & 3;

  // Per-lane masked weights over the 14-float span, packed as 7 pairs.
  v2f Wp2[7];
  #pragma unroll
  for (int j = 0; j < 7; ++j) {
    float w0, w1;
    {
      const int e = 2 * j;
      const int k = e - r;
      const int col = wbase + a + e;
      w0 = (k >= 0 && k <= 10 && col >= 0 && col < IMG_W) ? wk_lds[k] : 0.f;
    }
    {
      const int e = 2 * j + 1;
      const int k = e - r;
      const int col = wbase + a + e;
      w1 = (k >= 0 && k <= 10 && col >= 0 && col < IMG_W) ? wk_lds[k] : 0.f;
    }
    Wp2[j] = (v2f){w0, w1};
  }

  // DMA source: lanes 0..19 cover img1 floats 4l..4l+3 of the 80-float span,
  // lanes 20..39 cover img2 (landing at +80 via dest = base + lane*16).
  // wbase % 4 == 0, IMG_W % 4 == 0: each 4-float group entirely in- or
  // out-of-image; clamped addresses affect only fully-OOB groups (Wp-zeroed).
  const int li  = lane < 20 ? lane : lane - 20;
  const int c0r = wbase + 4 * li;
  const int c0  = c0r < 0 ? 0 : (c0r > IMG_W - 4 ? IMG_W - 4 : c0r);
  const float* srcbase = (lane < 20 ? p1 : p2) + c0;

  float* slw = &slice[wid][0][0];

  v2f Pm[12], Pq[12];   // ring: {m1,m2}, {qs,q12} per slot (48 VGPR)
  float acc = 0.f;
  int gr = y0 - 5;

  // Prologue: stage pairs for steps 0 (buf 0) and 1 (buf 1), oldest first.
  {
    const int q0 = gr     < 0 ? 0 : gr;
    const int q1 = gr + 1 < 0 ? 0 : gr + 1;
    const int q2 = gr + 2 < 0 ? 0 : gr + 2;
    const int q3 = gr + 3 < 0 ? 0 : gr + 3;
    if (lane < 40) {
      dma16(srcbase + (size_t)q0 * IMG_W, slw);
      dma16(srcbase + (size_t)q1 * IMG_W, slw + 160);
      dma16(srcbase + (size_t)q2 * IMG_W, slw + PAIRF);
      dma16(srcbase + (size_t)q3 * IMG_W, slw + PAIRF + 160);
    }
  }

  // 38 steps: s=0..5 warm the 12-slot ring; s=6..36 emit rows gr-7, gr-6
  // before HPASS; tail emits rows y0+62, y0+63 (phase 1, emit-only).
  STEP2(0, 0) STEP2(1, 0) STEP2(2, 0) STEP2(3, 0) STEP2(4, 0) STEP2(5, 0)
  #pragma unroll 1
  for (int it = 0; it < 5; ++it) {
    STEP2(0, 1) STEP2(1, 1) STEP2(2, 1) STEP2(3, 1) STEP2(4, 1) STEP2(5, 1)
  }
  STEP2(0, 1)
  { EMITQ(2) EMITQ(3) }

  // Block reduction.
  #pragma unroll
  for (int off = 32; off > 0; off >>= 1)
    acc += __shfl_down(acc, off, 64);
  if ((tid & 63) == 0) wave_sums[tid >> 6] = acc;
  __syncthreads();
  if (tid == 0)
    partial[bid] = wave_sums[0] + wave_sums[1] + wave_sums[2] + wave_sums[3];
}

__global__ __launch_bounds__(256) void ssim_reduce_kernel(
    const float* __restrict__ partial, float* __restrict__ out)
{
  const int tid = threadIdx.x;
  double acc = 0.0;
  for (int i = tid; i < NBLK; i += 256) acc += (double)partial[i];
  #pragma unroll
  for (int off = 32; off > 0; off >>= 1)
    acc += __shfl_down(acc, off, 64);
  __shared__ double wsums[4];
  if ((tid & 63) == 0) wsums[tid >> 6] = acc;
  __syncthreads();
  if (tid == 0) {
    const double total = wsums[0] + wsums[1] + wsums[2] + wsums[3];
    const double inv_n = 1.0 / ((double)N_PLANES * IMG_H * IMG_W);
    out[0] = (float)(total * inv_n);
  }
}

extern "C" void kernel_launch(void* const* d_in, const int* in_sizes, int n_in,
                              void* d_out, int out_size, void* d_ws, size_t ws_size,
                              hipStream_t stream)
{
  const float* img1 = (const float*)d_in[0];
  const float* img2 = (const float*)d_in[1];
  const float* kern = (const float*)d_in[2];
  float* out = (float*)d_out;
  float* partial = (float*)d_ws;   // NBLK floats = 3 KiB

  ssim_strip_kernel<<<NBLK, BLOCK, 0, stream>>>(img1, img2, kern, partial);
  ssim_reduce_kernel<<<1, 256, 0, stream>>>(partial, out);
}

// Round 18
// 56.566 us; speedup vs baseline: 1.0656x; 1.0656x over previous
//
#include <hip/hip_runtime.h>

// SSIM, fused separable, v16 = R16 + QS CHAIN-SPLIT ONLY (no load hoist).
// R17 showed the load-hoist's +16 VGPR cost more occupancy than its ILP
// bought (23->17%, 56.8->60.3us). This round isolates the other R17 change:
// R16's QS accumulator was a depth-14 dependent pk_fma chain (all others
// depth 7). Split QS -> QS1+QS2 (merged at ring-store, +2 VGPR): all chains
// depth 7. Pipeline and everything else byte-identical to R16 (56.8us best):
// DMA pair staging, triple pair-buffer, counted vmcnt(4), masked packed Wp2
// windows, EMIT-first ordering, packed fp32 H/V passes.

#define IMG_H 512
#define IMG_W 512
#define N_PLANES 48
#define KW 11
#define BLOCK 256
#define WAVE_COLS 64
#define STRIP_H 64
#define BLOCKS_X (IMG_W / (WAVE_COLS * 4))            // 2
#define BLOCKS_Y (IMG_H / STRIP_H)                    // 8
#define NBLK (N_PLANES * BLOCKS_X * BLOCKS_Y)         // 768
#define PAIRF 320          // floats per pair-buf: row0[img1 80|img2 80] row1[..]
#define C1_CONST 1.0e-4f
#define C2_CONST 9.0e-4f

typedef float v2f __attribute__((ext_vector_type(2)));
typedef float v4f __attribute__((ext_vector_type(4)));

typedef const __attribute__((address_space(1))) void GV;
typedef __attribute__((address_space(3))) void LV;

__device__ __forceinline__ void dma16(const float* g, float* l) {
  __builtin_amdgcn_global_load_lds((GV*)g, (LV*)l, 16, 0, 0);
}

__device__ __forceinline__ float bcastf(float x) {
  return __uint_as_float(__builtin_amdgcn_readfirstlane(__float_as_uint(x)));
}

#define VLO(V) __builtin_shufflevector(V, V, 0, 1)
#define VHI(V) __builtin_shufflevector(V, V, 2, 3)

// One packed 2-tap group; QS split across two accumulators so every
// accumulator chain is depth 7 (was: QS depth 14).
#define PTAP(WJ, X1, X2) { \
    const v2f t1_ = (WJ) * (X1); const v2f t2_ = (WJ) * (X2); \
    M1 += t1_; M2 += t2_; \
    QS1 += t1_ * (X1); QS2 += t2_ * (X2); Q12 += t1_ * (X2); }

// H-pass of one row from pair-slot base BP (img1 +0, img2 +80) into ring
// slot SLOT; zeros if ROW outside the image (zero-pad convolution).
#define HPASS(ROW, SLOT, BP) { \
  if ((ROW) >= 0 && (ROW) < IMG_H) { \
    const float* s1_ = (BP); const float* s2_ = (BP) + 80; \
    v2f M1 = {0.f,0.f}, M2 = {0.f,0.f}; \
    v2f QS1 = {0.f,0.f}, QS2 = {0.f,0.f}, Q12 = {0.f,0.f}; \
    { const v4f A0 = *(const v4f*)(s1_ + a); \
      const v4f B0 = *(const v4f*)(s2_ + a); \
      const v4f A1 = *(const v4f*)(s1_ + a + 4); \
      const v4f B1 = *(const v4f*)(s2_ + a + 4); \
      PTAP(Wp2[0], VLO(A0), VLO(B0)) PTAP(Wp2[1], VHI(A0), VHI(B0)) \
      PTAP(Wp2[2], VLO(A1), VLO(B1)) PTAP(Wp2[3], VHI(A1), VHI(B1)) } \
    { const v4f A2 = *(const v4f*)(s1_ + a + 8); \
      const v4f B2 = *(const v4f*)(s2_ + a + 8); \
      const v2f A3 = *(const v2f*)(s1_ + a + 12); \
      const v2f B3 = *(const v2f*)(s2_ + a + 12); \
      PTAP(Wp2[4], VLO(A2), VLO(B2)) PTAP(Wp2[5], VHI(A2), VHI(B2)) \
      PTAP(Wp2[6], A3, B3) } \
    const v2f QSs = QS1 + QS2; \
    Pm[(SLOT)] = (v2f){M1.x + M1.y, M2.x + M2.y}; \
    Pq[(SLOT)] = (v2f){QSs.x + QSs.y, Q12.x + Q12.y}; \
  } else { \
    Pm[(SLOT)] = (v2f){0.f, 0.f}; Pq[(SLOT)] = (v2f){0.f, 0.f}; } }

#define EMT(K, QQ) { const float w_ = wkr[(K)]; \
    vmP += w_ * Pm[(QQ)]; vqP += w_ * Pq[(QQ)]; }

// V-pass + SSIM for one output row whose tap-k ring slot is (OFF+K)%12.
#define EMITQ(OFF) { \
  v2f vmP = {0.f,0.f}, vqP = {0.f,0.f}; \
  EMT(0, ((OFF)+0)%12)  EMT(1, ((OFF)+1)%12)  EMT(2, ((OFF)+2)%12) \
  EMT(3, ((OFF)+3)%12)  EMT(4, ((OFF)+4)%12)  EMT(5, ((OFF)+5)%12) \
  EMT(6, ((OFF)+6)%12)  EMT(7, ((OFF)+7)%12)  EMT(8, ((OFF)+8)%12) \
  EMT(9, ((OFF)+9)%12)  EMT(10, ((OFF)+10)%12) \
  const float vm1_ = vmP.x, vm2_ = vmP.y, vqs_ = vqP.x, vq12_ = vqP.y; \
  const float mu11_ = vm1_ * vm1_; \
  const float mu22_ = vm2_ * vm2_; \
  const float mu12_ = vm1_ * vm2_; \
  const float musum_ = mu11_ + mu22_; \
  const float sigs_  = vqs_  - musum_; \
  const float sig12_ = vq12_ - mu12_; \
  const float num_ = (2.f * mu12_ + C1_CONST) * (2.f * sig12_ + C2_CONST); \
  const float den_ = (musum_ + C1_CONST) * (sigs_ + C2_CONST); \
  acc += num_ * __builtin_amdgcn_rcpf(den_); }

// One 2-row step, phase P = step % 6 (compile-time). EMIT-first:
// 1) issue DMA pair (gr+4, gr+5) -> buf (P+2)%3
// 2) if EMIT: output rows gr-7, gr-6 (ring-only; fills the DMA wait)
// 3) vmcnt(4): pair (gr, gr+1) (issued 2 steps ago) complete in buf P%3
// 4) HPASS rows gr, gr+1 -> slots (2P)%12, (2P+1)%12
#define STEP2(P, EMIT) { \
  { const int na_ = gr+4 < 0 ? 0 : (gr+4 > IMG_H-1 ? IMG_H-1 : gr+4); \
    const int nb_ = gr+5 < 0 ? 0 : (gr+5 > IMG_H-1 ? IMG_H-1 : gr+5); \
    if (lane < 40) { \
      float* d_ = slw + (((P)+2)%3) * PAIRF; \
      dma16(srcbase + (size_t)na_ * IMG_W, d_); \
      dma16(srcbase + (size_t)nb_ * IMG_W, d_ + 160); } } \
  if (EMIT) { EMITQ((2*(P))%12) EMITQ((2*(P)+1)%12) } \
  asm volatile("s_waitcnt vmcnt(4)" ::: "memory"); \
  __builtin_amdgcn_sched_barrier(0); \
  { const float* bp_ = slw + ((P)%3) * PAIRF; \
    HPASS(gr,     (2*(P))%12,     bp_) \
    HPASS(gr + 1, (2*(P)+1)%12,   bp_ + 160) } \
  gr += 2; }

__global__ __launch_bounds__(BLOCK) void ssim_strip_kernel(
    const float* __restrict__ img1,
    const float* __restrict__ img2,
    const float* __restrict__ kern2d,
    float* __restrict__ partial)
{
  // Wave-private triple pair-buffers: [wave][buf3][pair 320]. 15,360 B.
  __shared__ __align__(16) float slice[4][3][PAIRF];
  __shared__ float wk_lds[KW];
  __shared__ float wave_sums[BLOCK / 64];

  const int tid  = threadIdx.x;
  const int wid  = tid >> 6;
  const int lane = tid & 63;

  // 1D kernel = row sums of the normalized 2D kernel (== normalized 1D Gaussian).
  if (tid < KW) {
    float s = 0.f;
    #pragma unroll
    for (int j = 0; j < KW; ++j) s += kern2d[tid * KW + j];
    wk_lds[tid] = s;
  }
  __syncthreads();

  // V-pass weights, wave-uniform (SGPRs).
  float wkr[KW];
  #pragma unroll
  for (int k = 0; k < KW; ++k) wkr[k] = bcastf(wk_lds[k]);

  const int bid   = blockIdx.x;
  const int plane = bid / (BLOCKS_X * BLOCKS_Y);
  const int srem  = bid % (BLOCKS_X * BLOCKS_Y);
  const int y0    = (srem / BLOCKS_X) * STRIP_H;
  const int x0b   = (srem % BLOCKS_X) * (WAVE_COLS * 4);
  const float* __restrict__ p1 = img1 + (size_t)plane * IMG_H * IMG_W;
  const float* __restrict__ p2 = img2 + (size_t)plane * IMG_H * IMG_W;

  const int x0w   = x0b + wid * WAVE_COLS;   // wave's first column
  const int gx    = x0w + lane;              // this thread's output column
  const int wbase = x0w - 8;                 // slice float 0 <-> global col wbase

  // Lane's window: slice floats [a, a+13]; taps at e in [r, r+10].
  const int a = (lane + 3) & ~3;
  const int r = (lane + 3) & 3;

  // Per-lane masked weights over the 14-float span, packed as 7 pairs.
  v2f Wp2[7];
  #pragma unroll
  for (int j = 0; j < 7; ++j) {
    float w0, w1;
    {
      const int e = 2 * j;
      const int k = e - r;
      const int col = wbase + a + e;
      w0 = (k >= 0 && k <= 10 && col >= 0 && col < IMG_W) ? wk_lds[k] : 0.f;
    }
    {
      const int e = 2 * j + 1;
      const int k = e - r;
      const int col = wbase + a + e;
      w1 = (k >= 0 && k <= 10 && col >= 0 && col < IMG_W) ? wk_lds[k] : 0.f;
    }
    Wp2[j] = (v2f){w0, w1};
  }

  // DMA source: lanes 0..19 cover img1 floats 4l..4l+3 of the 80-float span,
  // lanes 20..39 cover img2 (landing at +80 via dest = base + lane*16).
  // wbase % 4 == 0, IMG_W % 4 == 0: each 4-float group entirely in- or
  // out-of-image; clamped addresses affect only fully-OOB groups (Wp-zeroed).
  const int li  = lane < 20 ? lane : lane - 20;
  const int c0r = wbase + 4 * li;
  const int c0  = c0r < 0 ? 0 : (c0r > IMG_W - 4 ? IMG_W - 4 : c0r);
  const float* srcbase = (lane < 20 ? p1 : p2) + c0;

  float* slw = &slice[wid][0][0];

  v2f Pm[12], Pq[12];   // ring: {m1,m2}, {qs,q12} per slot (48 VGPR)
  float acc = 0.f;
  int gr = y0 - 5;

  // Prologue: stage pairs for steps 0 (buf 0) and 1 (buf 1), oldest first.
  {
    const int q0 = gr     < 0 ? 0 : gr;
    const int q1 = gr + 1 < 0 ? 0 : gr + 1;
    const int q2 = gr + 2 < 0 ? 0 : gr + 2;
    const int q3 = gr + 3 < 0 ? 0 : gr + 3;
    if (lane < 40) {
      dma16(srcbase + (size_t)q0 * IMG_W, slw);
      dma16(srcbase + (size_t)q1 * IMG_W, slw + 160);
      dma16(srcbase + (size_t)q2 * IMG_W, slw + PAIRF);
      dma16(srcbase + (size_t)q3 * IMG_W, slw + PAIRF + 160);
    }
  }

  // 38 steps: s=0..5 warm the 12-slot ring; s=6..36 emit rows gr-7, gr-6
  // before HPASS; tail emits rows y0+62, y0+63 (phase 1, emit-only).
  STEP2(0, 0) STEP2(1, 0) STEP2(2, 0) STEP2(3, 0) STEP2(4, 0) STEP2(5, 0)
  #pragma unroll 1
  for (int it = 0; it < 5; ++it) {
    STEP2(0, 1) STEP2(1, 1) STEP2(2, 1) STEP2(3, 1) STEP2(4, 1) STEP2(5, 1)
  }
  STEP2(0, 1)
  { EMITQ(2) EMITQ(3) }

  // Block reduction.
  #pragma unroll
  for (int off = 32; off > 0; off >>= 1)
    acc += __shfl_down(acc, off, 64);
  if ((tid & 63) == 0) wave_sums[tid >> 6] = acc;
  __syncthreads();
  if (tid == 0)
    partial[bid] = wave_sums[0] + wave_sums[1] + wave_sums[2] + wave_sums[3];
}

__global__ __launch_bounds__(256) void ssim_reduce_kernel(
    const float* __restrict__ partial, float* __restrict__ out)
{
  const int tid = threadIdx.x;
  double acc = 0.0;
  for (int i = tid; i < NBLK; i += 256) acc += (double)partial[i];
  #pragma unroll
  for (int off = 32; off > 0; off >>= 1)
    acc += __shfl_down(acc, off, 64);
  __shared__ double wsums[4];
  if ((tid & 63) == 0) wsums[tid >> 6] = acc;
  __syncthreads();
  if (tid == 0) {
    const double total = wsums[0] + wsums[1] + wsums[2] + wsums[3];
    const double inv_n = 1.0 / ((double)N_PLANES * IMG_H * IMG_W);
    out[0] = (float)(total * inv_n);
  }
}

extern "C" void kernel_launch(void* const* d_in, const int* in_sizes, int n_in,
                              void* d_out, int out_size, void* d_ws, size_t ws_size,
                              hipStream_t stream)
{
  const float* img1 = (const float*)d_in[0];
  const float* img2 = (const float*)d_in[1];
  const float* kern = (const float*)d_in[2];
  float* out = (float*)d_out;
  float* partial = (float*)d_ws;   // NBLK floats = 3 KiB

  ssim_strip_kernel<<<NBLK, BLOCK, 0, stream>>>(img1, img2, kern, partial);
  ssim_reduce_kernel<<<1, 256, 0, stream>>>(partial, out);
}